// Round 6
// baseline (111.073 us; speedup 1.0000x reference)
//
#include <hip/hip_runtime.h>
#include <hip/hip_bf16.h>

// out[b,c,h,w] = (pol[b,r] * W_inj[c,r] + b_inj[c]) * 0.5 * M[b,0,h,w]
// r = (h/64)*8 + (w/64), pol = bits*2-1.
// B=16, C=3, H=W=512, N_BITS=64, GRID=8.
// img input is UNUSED by the math (shape only) -> never read it.
//
// One thread-iteration per (b, h, w4) float4 chunk: 1 vec4 load of M,
// 3 vec4 stores. M and out are streaming (touched once) -> nontemporal
// load/store so 67 MB doesn't cycle through L2 with zero reuse.
// Grid capped at 2048 blocks, grid-stride x2.
//
// NOTE: __builtin_nontemporal_* requires a NATIVE vector type, not HIP's
// float4 class -> use ext_vector_type(4).

#define B_ 16
#define H_ 512
#define W_ 512
#define W4_ (W_ / 4)          // 128 vec4 chunks per row
#define HW4_ (H_ * W4_)       // 65536 chunks per image plane
#define TOTAL4_ (B_ * HW4_)   // 1,048,576 vec4 chunks total

typedef float f32x4 __attribute__((ext_vector_type(4)));

__global__ __launch_bounds__(256) void spatial_encoder_kernel(
    const float* __restrict__ M,       // (B,1,H,W)
    const int* __restrict__ bits,      // (B,64)
    const float* __restrict__ W_inj,   // (3,64)
    const float* __restrict__ b_inj,   // (3,)
    float* __restrict__ out)           // (B,3,H,W)
{
    const float bi0 = b_inj[0], bi1 = b_inj[1], bi2 = b_inj[2];
    const f32x4* Mv = reinterpret_cast<const f32x4*>(M);
    f32x4* o = reinterpret_cast<f32x4*>(out);

    const int stride = gridDim.x * 256;
    for (int tid = blockIdx.x * 256 + threadIdx.x; tid < TOTAL4_; tid += stride) {
        const int b   = tid >> 16;          // tid / HW4_
        const int rem = tid & (HW4_ - 1);
        const int h   = rem >> 7;           // rem / W4_
        const int w4  = rem & (W4_ - 1);

        // region index: (h/64)*8 + (w/64); w = w4*4, so w/64 = w4/16
        const int r = ((h >> 6) << 3) + (w4 >> 4);

        const float pol = (float)(bits[(b << 6) + r]) * 2.0f - 1.0f;

        // per-channel scalar factor: f_c = 0.5*(pol*W_inj[c,r] + b_inj[c])
        const float f0 = 0.5f * (pol * W_inj[0 * 64 + r] + bi0);
        const float f1 = 0.5f * (pol * W_inj[1 * 64 + r] + bi1);
        const float f2 = 0.5f * (pol * W_inj[2 * 64 + r] + bi2);

        const f32x4 m = __builtin_nontemporal_load(&Mv[(size_t)b * HW4_ + rem]);

        const size_t base = ((size_t)b * 3) * HW4_ + rem;

        __builtin_nontemporal_store(m * f0, &o[base]);
        __builtin_nontemporal_store(m * f1, &o[base + HW4_]);
        __builtin_nontemporal_store(m * f2, &o[base + 2 * HW4_]);
    }
}

extern "C" void kernel_launch(void* const* d_in, const int* in_sizes, int n_in,
                              void* d_out, int out_size, void* d_ws, size_t ws_size,
                              hipStream_t stream) {
    // inputs: 0=img (UNUSED), 1=M, 2=bits, 3=W_inj, 4=b_inj
    const float* M     = (const float*)d_in[1];
    const int*   bits  = (const int*)d_in[2];
    const float* W_inj = (const float*)d_in[3];
    const float* b_inj = (const float*)d_in[4];
    float* out = (float*)d_out;

    const int grid = 2048;   // 8 blocks/CU on 256 CUs; grid-stride covers 2 chunks/thread

    spatial_encoder_kernel<<<grid, 256, 0, stream>>>(M, bits, W_inj, b_inj, out);
}

// Round 11
// 107.597 us; speedup vs baseline: 1.0323x; 1.0323x over previous
//
#include <hip/hip_runtime.h>

// out[b,c,h,w] = (pol[b,r] * W_inj[c,r] + b_inj[c]) * 0.5 * M[b,0,h,w]
// r = (h/64)*8 + (w/64), pol = bits*2-1.
// B=16, C=3, H=W=512, N_BITS=64, GRID=8.
// img input is UNUSED by the math (shape only) -> never read it.
//
// Round-6 evidence: kernel device time < 41 us (absent from top-5; harness
// ws-poison fills dominate at ~41.5 us, running 6.3-6.5 TB/s with CACHED
// stores). This round: drop the nontemporal hints (unproven on gfx950),
// one-shot grid (no loop), pure 32-bit indexing. 1 vec4 load + 3 vec4
// stores per thread, fully coalesced.

#define B_ 16
#define HW4_ 65536            // 512*512/4 vec4 chunks per image plane
#define TOTAL4_ (B_ * HW4_)   // 1,048,576 vec4 chunks total

typedef float f32x4 __attribute__((ext_vector_type(4)));

__global__ __launch_bounds__(256) void spatial_encoder_kernel(
    const f32x4* __restrict__ Mv,      // (B,1,H,W) as vec4
    const int* __restrict__ bits,      // (B,64)
    const float* __restrict__ W_inj,   // (3,64)
    const float* __restrict__ b_inj,   // (3,)
    f32x4* __restrict__ o)             // (B,3,H,W) as vec4
{
    const unsigned tid = blockIdx.x * 256u + threadIdx.x;  // 0 .. TOTAL4_-1
    const unsigned b   = tid >> 16;          // tid / HW4_
    const unsigned rem = tid & (HW4_ - 1);
    const unsigned h   = rem >> 7;           // rem / 128
    const unsigned w4  = rem & 127u;

    // region index: (h/64)*8 + (w/64); w = w4*4, so w/64 = w4/16
    const unsigned r = ((h >> 6) << 3) + (w4 >> 4);

    const float pol = (float)bits[(b << 6) + r] * 2.0f - 1.0f;

    // per-channel scalar factor: f_c = 0.5*(pol*W_inj[c,r] + b_inj[c])
    const float f0 = 0.5f * (pol * W_inj[r]       + b_inj[0]);
    const float f1 = 0.5f * (pol * W_inj[64 + r]  + b_inj[1]);
    const float f2 = 0.5f * (pol * W_inj[128 + r] + b_inj[2]);

    const f32x4 m = Mv[tid];                 // tid == b*HW4_ + rem

    const unsigned base = b * (3u * HW4_) + rem;  // < 3.15M, fits 32-bit
    o[base]             = m * f0;
    o[base + HW4_]      = m * f1;
    o[base + 2u * HW4_] = m * f2;
}

extern "C" void kernel_launch(void* const* d_in, const int* in_sizes, int n_in,
                              void* d_out, int out_size, void* d_ws, size_t ws_size,
                              hipStream_t stream) {
    // inputs: 0=img (UNUSED), 1=M, 2=bits, 3=W_inj, 4=b_inj
    const f32x4* Mv    = (const f32x4*)d_in[1];
    const int*   bits  = (const int*)d_in[2];
    const float* W_inj = (const float*)d_in[3];
    const float* b_inj = (const float*)d_in[4];
    f32x4* out = (f32x4*)d_out;

    spatial_encoder_kernel<<<TOTAL4_ / 256, 256, 0, stream>>>(Mv, bits, W_inj, b_inj, out);
}